// Round 14
// baseline (78.237 us; speedup 1.0000x reference)
//
#include <hip/hip_runtime.h>
#include <hip/hip_bf16.h>
#include <math.h>

typedef __attribute__((ext_vector_type(4))) float f32x4;
typedef __attribute__((ext_vector_type(8))) short bf16x8;     // 8 bf16 in 4 VGPRs
typedef __attribute__((ext_vector_type(4))) unsigned short u16x4;
typedef __attribute__((ext_vector_type(8))) unsigned short u16x8;
typedef __attribute__((ext_vector_type(2))) unsigned int u32x2;

__device__ __forceinline__ unsigned short f2b(float f) {
  unsigned int u = __builtin_bit_cast(unsigned int, f);
  u += 0x7fffu + ((u >> 16) & 1u);          // RNE
  return (unsigned short)(u >> 16);
}
__device__ __forceinline__ float b2f(unsigned short u) {
  unsigned int v = ((unsigned int)u) << 16;
  return __builtin_bit_cast(float, v);
}
__device__ __forceinline__ float gelu_exact(float x) {
  return 0.5f * x * (1.0f + erff(x * 0.70710678118654752440f));
}

// barrier with LDS-visibility only: global loads stay in flight (T4; rule #18 fence)
#define LBAR do {                                               \
    asm volatile("s_waitcnt lgkmcnt(0)" ::: "memory");          \
    __builtin_amdgcn_s_barrier();                               \
    __builtin_amdgcn_sched_barrier(0);                          \
  } while (0)

// ---------------- prep: token MLP hiddens + weight conversions ----------------
__global__ void prep(const float* __restrict__ tokens,
                     const float* __restrict__ Wk1, const float* __restrict__ Wv1,
                     const float* __restrict__ Wk2, const float* __restrict__ Wv2,
                     unsigned short* __restrict__ hkb, unsigned short* __restrict__ hvTb,
                     unsigned short* __restrict__ Wk2b, unsigned short* __restrict__ Wv2Tb) {
  const int tid = threadIdx.x;
  const int bx = blockIdx.x;
  if (bx < 256) {
    __shared__ float tok[4][64];
    const int tl = tid >> 6, j = tid & 63;
    const int t0 = bx * 4;
    tok[tl][j] = tokens[(size_t)(t0 + tl) * 64 + j];
    __syncthreads();
    float sk = 0.f, sv = 0.f;
    #pragma unroll 16
    for (int i = 0; i < 64; ++i) {
      float tv = tok[tl][i];
      sk += tv * Wk1[i * 64 + j];
      sv += tv * Wv1[i * 64 + j];
    }
    hkb[(size_t)(t0 + tl) * 64 + j]  = f2b(gelu_exact(sk));
    hvTb[(size_t)j * 1024 + t0 + tl] = f2b(gelu_exact(sv));
  } else if (bx < 272) {
    const int b = bx - 256;
    for (int i = 0; i < 8; ++i) {
      int idx = b * 2048 + i * 256 + tid;
      f32x4 v = ((const f32x4*)Wk2)[idx];
      u16x4 o; o[0] = f2b(v[0]); o[1] = f2b(v[1]); o[2] = f2b(v[2]); o[3] = f2b(v[3]);
      ((u16x4*)Wk2b)[idx] = o;
    }
  } else {
    __shared__ float t[64][65];
    const int f0 = (bx - 272) * 64;
    for (int i = 0; i < 16; ++i) {
      int idx = i * 256 + tid; int r = idx >> 6, c = idx & 63;   // r=j, c=f
      t[r][c] = Wv2[(size_t)r * 2048 + f0 + c];
    }
    __syncthreads();
    for (int i = 0; i < 16; ++i) {
      int idx = i * 256 + tid; int r = idx >> 6, c = idx & 63;   // r=f, c=j
      Wv2Tb[(size_t)(f0 + r) * 64 + c] = f2b(t[c][r]);
    }
  }
}

// ---------------- fused main: 512 blocks x 32 rows, 47KB LDS -> 3 blocks/CU ----------------
// P1: single-buffer As/Bs, 2-LBAR steps, depth-2 reg prefetch (loads live across barriers).
// P2: token-chunked (2x128): chunk0 raw-sim bf16 in LDS, chunk1 in regs; gelu at read.
// P3: single Ws/oS, 2-LBAR steps, depth-2 prefetch, coalesced stores.
// Arena 48128B: xw16@0(4608) wvs@4608(4096) | overlay@8704:
//   P1 As@8704(8192) Bs@16896(16384); red@8704(8192, post-loop)
//   P2 per-wave 9728B regions @8704 (Pl[32][152] then redw 8192B); redn@47616(512)
//   P3 Ws@8704(16384) oS@25088(16896)
__global__ __launch_bounds__(256, 3)
void mainK(const float* __restrict__ x,
           const unsigned short* __restrict__ Wk2b,
           const unsigned short* __restrict__ hkb,
           const unsigned short* __restrict__ hvTb,
           const unsigned short* __restrict__ Wv2Tb,
           float* __restrict__ out) {
  __shared__ __align__(16) char smraw[48128];
  unsigned short (*xw16)[72] = (unsigned short(*)[72])smraw;              // [32][72]
  unsigned short* wvs = (unsigned short*)(smraw + 4608);                  // [32*64]
  unsigned short* As  = (unsigned short*)(smraw + 8704);                  // [4096]
  unsigned short* Bs  = (unsigned short*)(smraw + 16896);                 // [8192]
  float (*red)[4][64][4] = (float(*)[4][64][4])(smraw + 8704);            // [2][4][64][4]
  float (*redn)[2][16] = (float(*)[2][16])(smraw + 47616);                // [4][2][16]
  unsigned short* Ws  = (unsigned short*)(smraw + 8704);                  // [8192]
  float (*oS)[132] = (float(*)[132])(smraw + 25088);                      // [32][132]

  const int tid = threadIdx.x, wave = tid >> 6, lane = tid & 63;
  const int lrow = lane & 15, q = lane >> 4;
  const int r0 = blockIdx.x * 32;
  const int tw = wave * 256;

  // ================= phase 1: xp32 = x32 @ Wk2b^T =================
  {
    const int mt = wave & 1, h = wave >> 1;
    f32x4 aR0[4], aR1[4]; u16x8 bR0[4], bR1[4];
    f32x4 acc[4] = {};

#define P1_LOAD(sidx, AR, BR)                                                             \
    do { _Pragma("unroll") for (int i = 0; i < 4; ++i) {                                  \
      int u4 = (wave * 4 + i) * 4 + (lane >> 4); int rr = u4 >> 1, ah = u4 & 1;           \
      AR[i] = *(const f32x4*)&x[(size_t)(r0 + rr) * 2048 + ah * 1024 + (sidx) * 64 + (lane & 15) * 4]; \
      int lin = (wave * 4 + i) * 8 + (lane >> 3); int t = lin >> 1, bh = lin & 1;         \
      BR[i] = *(const u16x8*)&Wk2b[(size_t)t * 2048 + bh * 1024 + (sidx) * 64 + (lane & 7) * 8]; \
    } } while (0)

#define P1_WRITE(AR, BR)                                                                  \
    do { _Pragma("unroll") for (int i = 0; i < 4; ++i) {                                  \
      int u4 = (wave * 4 + i) * 4 + (lane >> 4); int rr = u4 >> 1, ah = u4 & 1;           \
      int uu = ((lane & 15) >> 1) ^ (rr & 7); u16x4 o;                                    \
      o[0] = f2b(AR[i][0]); o[1] = f2b(AR[i][1]); o[2] = f2b(AR[i][2]); o[3] = f2b(AR[i][3]); \
      *(u16x4*)&As[(rr * 2 + ah) * 64 + (uu << 3) + (lane & 1) * 4] = o;                  \
      int lin = (wave * 4 + i) * 8 + (lane >> 3); int t = lin >> 1, bh = lin & 1;         \
      *(u16x8*)&Bs[(t * 2 + bh) * 64 + (((lane & 7) ^ (t & 7)) << 3)] = BR[i];            \
    } } while (0)

#define P1_COMP()                                                                         \
    do { _Pragma("unroll") for (int kk = 0; kk < 2; ++kk) {                               \
      const int ar = mt * 16 + lrow;                                                      \
      bf16x8 af = *(const bf16x8*)&As[(ar * 2 + h) * 64 + (((kk * 4 + q) ^ (ar & 7)) << 3)]; \
      _Pragma("unroll") for (int nt = 0; nt < 4; ++nt) {                                  \
        const int br = nt * 16 + lrow;                                                    \
        bf16x8 bf = *(const bf16x8*)&Bs[(br * 2 + h) * 64 + (((kk * 4 + q) ^ (br & 7)) << 3)]; \
        acc[nt] = __builtin_amdgcn_mfma_f32_16x16x32_bf16(af, bf, acc[nt], 0, 0, 0);      \
      } } } while (0)

    P1_LOAD(0, aR0, bR0);
    P1_LOAD(1, aR1, bR1);
    #pragma unroll 1
    for (int s2 = 0; s2 < 16; s2 += 2) {
      P1_WRITE(aR0, bR0);
      LBAR;
      P1_COMP();
      if (s2 + 2 < 16) P1_LOAD(s2 + 2, aR0, bR0);
      LBAR;
      P1_WRITE(aR1, bR1);
      LBAR;
      P1_COMP();
      if (s2 + 3 < 16) P1_LOAD(s2 + 3, aR1, bR1);
      LBAR;
    }
#undef P1_LOAD
#undef P1_WRITE
#undef P1_COMP

    // cross-half reduce -> xw16 (red overlays As/Bs, dead after final LBAR)
    if (h == 1) {
      #pragma unroll
      for (int nt = 0; nt < 4; ++nt) *(f32x4*)&red[mt][nt][lane][0] = acc[nt];
    }
    LBAR;
    if (h == 0) {
      #pragma unroll
      for (int nt = 0; nt < 4; ++nt) {
        f32x4 s2v = acc[nt] + *(const f32x4*)&red[mt][nt][lane][0];
        #pragma unroll
        for (int r = 0; r < 4; ++r)
          xw16[mt * 16 + q * 4 + r][nt * 16 + lrow] = f2b(s2v[r]);
      }
    }
    LBAR;
  }

  // ================= phase 2: sim -> norm -> gelu -> wv (token-chunked) =================
  {
    char* reg_w = smraw + 8704 + wave * 9728;
    unsigned short (*PlW)[152] = (unsigned short(*)[152])reg_w;

    bf16x8 xb[2][2];
    #pragma unroll
    for (int mi = 0; mi < 2; ++mi)
      #pragma unroll
      for (int kk = 0; kk < 2; ++kk)
        xb[mi][kk] = *(const bf16x8*)&xw16[mi * 16 + lrow][kk * 32 + q * 8];

    float ss[2] = {0.f, 0.f};

    // chunk 0 (tokens tw..tw+127): MFMA -> sumsq -> raw sim bf16 -> Pl
    {
      f32x4 a0[8][2] = {};
      #pragma unroll
      for (int t8 = 0; t8 < 8; ++t8)
        #pragma unroll
        for (int kk = 0; kk < 2; ++kk) {
          bf16x8 a = *(const bf16x8*)&hkb[(size_t)(tw + t8 * 16 + lrow) * 64 + kk * 32 + q * 8];
          #pragma unroll
          for (int mi = 0; mi < 2; ++mi)
            a0[t8][mi] = __builtin_amdgcn_mfma_f32_16x16x32_bf16(a, xb[mi][kk], a0[t8][mi], 0, 0, 0);
        }
      #pragma unroll
      for (int t8 = 0; t8 < 8; ++t8)
        #pragma unroll
        for (int mi = 0; mi < 2; ++mi) {
          #pragma unroll
          for (int r = 0; r < 4; ++r) ss[mi] += a0[t8][mi][r] * a0[t8][mi][r];
          u32x2 pw;
          pw[0] = (unsigned)f2b(a0[t8][mi][0]) | ((unsigned)f2b(a0[t8][mi][1]) << 16);
          pw[1] = (unsigned)f2b(a0[t8][mi][2]) | ((unsigned)f2b(a0[t8][mi][3]) << 16);
          *(u32x2*)&PlW[mi * 16 + lrow][t8 * 16 + q * 4] = pw;    // RAW sim (bf16)
        }
    }
    // chunk 1 (tokens tw+128..): MFMA, keep in regs
    f32x4 a1[8][2] = {};
    #pragma unroll
    for (int t8 = 0; t8 < 8; ++t8)
      #pragma unroll
      for (int kk = 0; kk < 2; ++kk) {
        bf16x8 a = *(const bf16x8*)&hkb[(size_t)(tw + 128 + t8 * 16 + lrow) * 64 + kk * 32 + q * 8];
        #pragma unroll
        for (int mi = 0; mi < 2; ++mi)
          a1[t8][mi] = __builtin_amdgcn_mfma_f32_16x16x32_bf16(a, xb[mi][kk], a1[t8][mi], 0, 0, 0);
      }
    #pragma unroll
    for (int t8 = 0; t8 < 8; ++t8)
      #pragma unroll
      for (int mi = 0; mi < 2; ++mi)
        #pragma unroll
        for (int r = 0; r < 4; ++r) ss[mi] += a1[t8][mi][r] * a1[t8][mi][r];

    // row-sum reduce -> scale
    #pragma unroll
    for (int mi = 0; mi < 2; ++mi) {
      ss[mi] += __shfl_xor(ss[mi], 16, 64);
      ss[mi] += __shfl_xor(ss[mi], 32, 64);
    }
    if (q == 0) { redn[wave][0][lrow] = ss[0]; redn[wave][1][lrow] = ss[1]; }
    LBAR;
    float scale[2];
    #pragma unroll
    for (int mi = 0; mi < 2; ++mi) {
      float t = redn[0][mi][lrow] + redn[1][mi][lrow] + redn[2][mi][lrow] + redn[3][mi][lrow];
      scale[mi] = 32.0f * rsqrtf(fmaxf(t, 1e-20f));
    }

    // wva chunk 0: raw from Pl -> gelu at read -> MFMA
    f32x4 wva[2][4] = {};
    #pragma unroll
    for (int kc = 0; kc < 4; ++kc) {
      u16x8 r0v = *(const u16x8*)&PlW[lrow][kc * 32 + q * 8];
      u16x8 r1v = *(const u16x8*)&PlW[16 + lrow][kc * 32 + q * 8];
      u16x8 p0, p1;
      #pragma unroll
      for (int j = 0; j < 8; ++j) {
        p0[j] = f2b(gelu_exact(b2f(r0v[j]) * scale[0]));
        p1[j] = f2b(gelu_exact(b2f(r1v[j]) * scale[1]));
      }
      bf16x8 pa0 = __builtin_bit_cast(bf16x8, p0);
      bf16x8 pa1 = __builtin_bit_cast(bf16x8, p1);
      #pragma unroll
      for (int nt = 0; nt < 4; ++nt) {
        bf16x8 b = *(const bf16x8*)&hvTb[(size_t)(nt * 16 + lrow) * 1024 + tw + kc * 32 + q * 8];
        wva[0][nt] = __builtin_amdgcn_mfma_f32_16x16x32_bf16(pa0, b, wva[0][nt], 0, 0, 0);
        wva[1][nt] = __builtin_amdgcn_mfma_f32_16x16x32_bf16(pa1, b, wva[1][nt], 0, 0, 0);
      }
    }
    // chunk 1: gelu'd P -> Pl (same-wave in-order after reads above), then wva
    #pragma unroll
    for (int t8 = 0; t8 < 8; ++t8)
      #pragma unroll
      for (int mi = 0; mi < 2; ++mi) {
        float g0 = gelu_exact(a1[t8][mi][0] * scale[mi]);
        float g1 = gelu_exact(a1[t8][mi][1] * scale[mi]);
        float g2 = gelu_exact(a1[t8][mi][2] * scale[mi]);
        float g3 = gelu_exact(a1[t8][mi][3] * scale[mi]);
        u32x2 pw;
        pw[0] = (unsigned)f2b(g0) | ((unsigned)f2b(g1) << 16);
        pw[1] = (unsigned)f2b(g2) | ((unsigned)f2b(g3) << 16);
        *(u32x2*)&PlW[mi * 16 + lrow][t8 * 16 + q * 4] = pw;
      }
    #pragma unroll
    for (int kc = 0; kc < 4; ++kc) {
      bf16x8 pa0 = *(const bf16x8*)&PlW[lrow][kc * 32 + q * 8];
      bf16x8 pa1 = *(const bf16x8*)&PlW[16 + lrow][kc * 32 + q * 8];
      #pragma unroll
      for (int nt = 0; nt < 4; ++nt) {
        bf16x8 b = *(const bf16x8*)&hvTb[(size_t)(nt * 16 + lrow) * 1024 + tw + 128 + kc * 32 + q * 8];
        wva[0][nt] = __builtin_amdgcn_mfma_f32_16x16x32_bf16(pa0, b, wva[0][nt], 0, 0, 0);
        wva[1][nt] = __builtin_amdgcn_mfma_f32_16x16x32_bf16(pa1, b, wva[1][nt], 0, 0, 0);
      }
    }

    // cross-wave K-reduce via per-wave regions (redw overlays Pl, same-wave ordered)
    #pragma unroll
    for (int mi = 0; mi < 2; ++mi)
      #pragma unroll
      for (int nt = 0; nt < 4; ++nt)
        *(f32x4*)(reg_w + (size_t)((mi * 4 + nt) * 64 + lane) * 16) = wva[mi][nt];
    LBAR;
    #pragma unroll
    for (int mi = 0; mi < 2; ++mi) {
      f32x4 s = *(const f32x4*)(smraw + 8704 + 0 * 9728 + (size_t)((mi * 4 + wave) * 64 + lane) * 16);
      s += *(const f32x4*)(smraw + 8704 + 1 * 9728 + (size_t)((mi * 4 + wave) * 64 + lane) * 16);
      s += *(const f32x4*)(smraw + 8704 + 2 * 9728 + (size_t)((mi * 4 + wave) * 64 + lane) * 16);
      s += *(const f32x4*)(smraw + 8704 + 3 * 9728 + (size_t)((mi * 4 + wave) * 64 + lane) * 16);
      #pragma unroll
      for (int r = 0; r < 4; ++r) {
        int m = mi * 16 + q * 4 + r, j = wave * 16 + lrow;
        wvs[m * 64 + (((j >> 3) ^ (m & 7)) << 3) + (j & 7)] = f2b(s[r]);
      }
    }
    LBAR;
  }

  // ================= phase 3: out32x2048 = wv32 @ Wv2T^T =================
  {
    u16x8 wR0[4], wR1[4];

#define P3_LOAD(fcx, WR)                                                                  \
    do { _Pragma("unroll") for (int i = 0; i < 4; ++i) {                                  \
      int lin = (wave * 4 + i) * 64 + lane; int frow = lin >> 3, u = lin & 7;             \
      WR[i] = *(const u16x8*)&Wv2Tb[(size_t)((fcx) * 128 + frow) * 64 + u * 8];           \
    } } while (0)
#define P3_WRITE(WR)                                                                      \
    do { _Pragma("unroll") for (int i = 0; i < 4; ++i) {                                  \
      int lin = (wave * 4 + i) * 64 + lane; int frow = lin >> 3, u = lin & 7;             \
      *(u16x8*)&Ws[frow * 64 + ((u ^ (frow & 7)) << 3)] = WR[i];                          \
    } } while (0)
#define P3_COMP()                                                                         \
    do { _Pragma("unroll") for (int ftl = 0; ftl < 2; ++ftl) {                            \
      const int ft = wave * 2 + ftl;                                                      \
      f32x4 a2[2] = {};                                                                   \
      _Pragma("unroll") for (int kk = 0; kk < 2; ++kk) {                                  \
        const int frow = ft * 16 + lrow;                                                  \
        bf16x8 af = *(const bf16x8*)&Ws[frow * 64 + (((kk * 4 + q) ^ (frow & 7)) << 3)];  \
        _Pragma("unroll") for (int mt = 0; mt < 2; ++mt)                                  \
          a2[mt] = __builtin_amdgcn_mfma_f32_16x16x32_bf16(af, bw[mt][kk], a2[mt], 0, 0, 0); \
      }                                                                                   \
      _Pragma("unroll") for (int mt = 0; mt < 2; ++mt)                                    \
        *(f32x4*)&oS[mt * 16 + lrow][ft * 16 + q * 4] = a2[mt];                           \
    } } while (0)
#define P3_STORE(fcx)                                                                     \
    do { _Pragma("unroll") for (int i = 0; i < 4; ++i) {                                  \
      int row = (wave * 4 + i) * 2 + (lane >> 5); int c = (lane & 31) * 4;                \
      f32x4 v = *(const f32x4*)&oS[row][c];                                               \
      *(f32x4*)&out[(size_t)(r0 + row) * 2048 + (fcx) * 128 + c] = v;                     \
    } } while (0)

    P3_LOAD(0, wR0);
    P3_LOAD(1, wR1);

    bf16x8 bw[2][2];
    #pragma unroll
    for (int mt = 0; mt < 2; ++mt)
      #pragma unroll
      for (int kk = 0; kk < 2; ++kk) {
        int row = mt * 16 + lrow;
        bw[mt][kk] = *(const bf16x8*)&wvs[row * 64 + (((kk * 4 + q) ^ (row & 7)) << 3)];
      }

    #pragma unroll 1
    for (int fc2 = 0; fc2 < 16; fc2 += 2) {
      P3_WRITE(wR0);
      LBAR;
      P3_COMP();
      if (fc2 + 2 < 16) P3_LOAD(fc2 + 2, wR0);
      LBAR;
      P3_STORE(fc2);
      P3_WRITE(wR1);
      LBAR;
      P3_COMP();
      if (fc2 + 3 < 16) P3_LOAD(fc2 + 3, wR1);
      LBAR;
      P3_STORE(fc2 + 1);
    }
#undef P3_LOAD
#undef P3_WRITE
#undef P3_COMP
#undef P3_STORE
  }
}

extern "C" void kernel_launch(void* const* d_in, const int* in_sizes, int n_in,
                              void* d_out, int out_size, void* d_ws, size_t ws_size,
                              hipStream_t stream) {
  (void)in_sizes; (void)n_in; (void)out_size; (void)ws_size;
  const float* x      = (const float*)d_in[0];
  const float* tokens = (const float*)d_in[1];
  const float* Wk1    = (const float*)d_in[2];
  const float* Wk2    = (const float*)d_in[3];
  const float* Wv1    = (const float*)d_in[4];
  const float* Wv2    = (const float*)d_in[5];

  char* ws = (char*)d_ws;
  unsigned short* hkb   = (unsigned short*)(ws);                    // 128 KB
  unsigned short* hvTb  = (unsigned short*)(ws + 131072);           // 128 KB
  unsigned short* Wk2b  = (unsigned short*)(ws + 262144);           // 256 KB
  unsigned short* Wv2Tb = (unsigned short*)(ws + 524288);           // 256 KB

  hipLaunchKernelGGL(prep, dim3(304), dim3(256), 0, stream,
                     tokens, Wk1, Wv1, Wk2, Wv2, hkb, hvTb, Wk2b, Wv2Tb);
  hipLaunchKernelGGL(mainK, dim3(512), dim3(256), 0, stream,
                     x, Wk2b, hkb, hvTb, Wv2Tb, (float*)d_out);
}

// Round 15
// 73.869 us; speedup vs baseline: 1.0591x; 1.0591x over previous
//
#include <hip/hip_runtime.h>
#include <hip/hip_bf16.h>
#include <math.h>

typedef __attribute__((ext_vector_type(4))) float f32x4;
typedef __attribute__((ext_vector_type(8))) short bf16x8;     // 8 bf16 in 4 VGPRs
typedef __attribute__((ext_vector_type(4))) unsigned short u16x4;
typedef __attribute__((ext_vector_type(8))) unsigned short u16x8;
typedef __attribute__((ext_vector_type(2))) unsigned int u32x2;

__device__ __forceinline__ unsigned short f2b(float f) {
  unsigned int u = __builtin_bit_cast(unsigned int, f);
  u += 0x7fffu + ((u >> 16) & 1u);          // RNE
  return (unsigned short)(u >> 16);
}
__device__ __forceinline__ float gelu_exact(float x) {
  return 0.5f * x * (1.0f + erff(x * 0.70710678118654752440f));
}
// tanh-form gelu via sigmoid: gelu(x) ~= x * sigma(1.5957691(x + 0.044715 x^3))
// max abs dev from exact ~3e-4 -> ~1e-4 in out (budget 0.154).  [P2 only]
__device__ __forceinline__ float gelu_fast(float x) {
  float z = 1.5957691f * x * fmaf(0.044715f, x * x, 1.0f);
  return x / (1.0f + __expf(-z));
}

// ---------------- prep: token MLP hiddens + weight conversions ----------------
__global__ void prep(const float* __restrict__ tokens,
                     const float* __restrict__ Wk1, const float* __restrict__ Wv1,
                     const float* __restrict__ Wk2, const float* __restrict__ Wv2,
                     unsigned short* __restrict__ hkb, unsigned short* __restrict__ hvTb,
                     unsigned short* __restrict__ Wk2b, unsigned short* __restrict__ Wv2Tb) {
  const int tid = threadIdx.x;
  const int bx = blockIdx.x;
  if (bx < 256) {
    __shared__ float tok[4][64];
    const int tl = tid >> 6, j = tid & 63;
    const int t0 = bx * 4;
    tok[tl][j] = tokens[(size_t)(t0 + tl) * 64 + j];
    __syncthreads();
    float sk = 0.f, sv = 0.f;
    #pragma unroll 16
    for (int i = 0; i < 64; ++i) {
      float tv = tok[tl][i];
      sk += tv * Wk1[i * 64 + j];
      sv += tv * Wv1[i * 64 + j];
    }
    hkb[(size_t)(t0 + tl) * 64 + j]  = f2b(gelu_exact(sk));
    hvTb[(size_t)j * 1024 + t0 + tl] = f2b(gelu_exact(sv));
  } else if (bx < 272) {
    const int b = bx - 256;
    for (int i = 0; i < 8; ++i) {
      int idx = b * 2048 + i * 256 + tid;
      f32x4 v = ((const f32x4*)Wk2)[idx];
      u16x4 o; o[0] = f2b(v[0]); o[1] = f2b(v[1]); o[2] = f2b(v[2]); o[3] = f2b(v[3]);
      ((u16x4*)Wk2b)[idx] = o;
    }
  } else {
    __shared__ float t[64][65];
    const int f0 = (bx - 272) * 64;
    for (int i = 0; i < 16; ++i) {
      int idx = i * 256 + tid; int r = idx >> 6, c = idx & 63;   // r=j, c=f
      t[r][c] = Wv2[(size_t)r * 2048 + f0 + c];
    }
    __syncthreads();
    for (int i = 0; i < 16; ++i) {
      int idx = i * 256 + tid; int r = idx >> 6, c = idx & 63;   // r=f, c=j
      Wv2Tb[(size_t)(f0 + r) * 64 + c] = f2b(t[c][r]);
    }
  }
}

// ---------------- fused main (R13 structure + nt-stores + fast gelu) ----------------
// 512 blocks x 256 thr, 32 rows/block, 75 KB arena, 2 blocks/CU.
__global__ __launch_bounds__(256, 2)
void mainK(const float* __restrict__ x,
           const unsigned short* __restrict__ Wk2b,
           const unsigned short* __restrict__ hkb,
           const unsigned short* __restrict__ hvTb,
           const unsigned short* __restrict__ Wv2Tb,
           float* __restrict__ out) {
  __shared__ __align__(16) char smraw[76800];
  // phase-1 views
  unsigned short* As = (unsigned short*)smraw;                                  // [2][4096]
  unsigned short* Bs = (unsigned short*)(smraw + 16384);                        // [2][8192]
  float (*red)[4][64][4] = (float(*)[4][64][4])(smraw + 49152);                 // [2][4][64][4]
  unsigned short (*xw16)[72] = (unsigned short(*)[72])(smraw + 57344);          // [32][72]
  // phase-2 views
  unsigned short (*Pl)[32][152] = (unsigned short(*)[32][152])smraw;            // [4][32][152]
  float (*redn)[2][16] = (float(*)[2][16])(smraw + 38912);                      // [4][2][16]
  float (*redw)[2][4][64][4] = (float(*)[2][4][64][4])(smraw + 39424);          // [4][2][4][64][4]
  // phase-3 views
  unsigned short* Ws = (unsigned short*)smraw;                                  // [2][8192]
  unsigned short* wvs = (unsigned short*)(smraw + 32768);                       // [2048]
  float (*oS)[32][136] = (float(*)[32][136])(smraw + 36864);                    // [2][32][136]

  const int tid = threadIdx.x, wave = tid >> 6, lane = tid & 63;
  const int lrow = lane & 15, q = lane >> 4;
  const int r0 = blockIdx.x * 32;
  const int tw = wave * 256;

  // ================= phase 1: xp32 = x32 @ Wk2b^T =================
  {
    const int mt = wave & 1, h = wave >> 1;
    f32x4 aR[4]; u16x8 bR[4];
    f32x4 acc[4] = {};

#define P1_LOAD(sidx)                                                                     \
    do { _Pragma("unroll") for (int i = 0; i < 4; ++i) {                                  \
      int u4 = (wave * 4 + i) * 4 + (lane >> 4); int rr = u4 >> 1, ah = u4 & 1;           \
      aR[i] = *(const f32x4*)&x[(size_t)(r0 + rr) * 2048 + ah * 1024 + (sidx) * 64 + (lane & 15) * 4]; \
      int lin = (wave * 4 + i) * 8 + (lane >> 3); int t = lin >> 1, bh = lin & 1;         \
      bR[i] = *(const u16x8*)&Wk2b[(size_t)t * 2048 + bh * 1024 + (sidx) * 64 + (lane & 7) * 8]; \
    } } while (0)

#define P1_WRITE(buf)                                                                     \
    do { _Pragma("unroll") for (int i = 0; i < 4; ++i) {                                  \
      int u4 = (wave * 4 + i) * 4 + (lane >> 4); int rr = u4 >> 1, ah = u4 & 1;           \
      int uu = ((lane & 15) >> 1) ^ (rr & 7); u16x4 o;                                    \
      o[0] = f2b(aR[i][0]); o[1] = f2b(aR[i][1]); o[2] = f2b(aR[i][2]); o[3] = f2b(aR[i][3]); \
      *(u16x4*)&As[(buf) * 4096 + (rr * 2 + ah) * 64 + (uu << 3) + (lane & 1) * 4] = o;   \
      int lin = (wave * 4 + i) * 8 + (lane >> 3); int t = lin >> 1, bh = lin & 1;         \
      *(u16x8*)&Bs[(buf) * 8192 + (t * 2 + bh) * 64 + (((lane & 7) ^ (t & 7)) << 3)] = bR[i]; \
    } } while (0)

    P1_LOAD(0);
    P1_WRITE(0);
    P1_LOAD(1);
    __syncthreads();

    #pragma unroll 1
    for (int s = 0; s < 16; ++s) {
      const int cb = s & 1, nb = cb ^ 1;
      if (s + 1 < 16) P1_WRITE(nb);          // regs for step s+1 (loaded at s-1)
      if (s + 2 < 16) P1_LOAD(s + 2);        // lands during compute + next iter
      #pragma unroll
      for (int kk = 0; kk < 2; ++kk) {
        const int ar = mt * 16 + lrow;
        bf16x8 af = *(const bf16x8*)&As[cb * 4096 + (ar * 2 + h) * 64 + (((kk * 4 + q) ^ (ar & 7)) << 3)];
        #pragma unroll
        for (int nt = 0; nt < 4; ++nt) {
          const int br = nt * 16 + lrow;
          bf16x8 bf = *(const bf16x8*)&Bs[cb * 8192 + (br * 2 + h) * 64 + (((kk * 4 + q) ^ (br & 7)) << 3)];
          acc[nt] = __builtin_amdgcn_mfma_f32_16x16x32_bf16(af, bf, acc[nt], 0, 0, 0);
        }
      }
      __syncthreads();
    }
#undef P1_LOAD
#undef P1_WRITE

    // cross-half reduce -> xw16 (LDS)
    if (h == 1) {
      #pragma unroll
      for (int nt = 0; nt < 4; ++nt) *(f32x4*)&red[mt][nt][lane][0] = acc[nt];
    }
    __syncthreads();
    if (h == 0) {
      #pragma unroll
      for (int nt = 0; nt < 4; ++nt) {
        f32x4 s2 = acc[nt] + *(const f32x4*)&red[mt][nt][lane][0];
        #pragma unroll
        for (int r = 0; r < 4; ++r)
          xw16[mt * 16 + q * 4 + r][nt * 16 + lrow] = f2b(s2[r]);
      }
    }
    __syncthreads();
  }

  // ================= phase 2: sim -> norm -> gelu -> wv (on-chip) =================
  {
    bf16x8 xb[2][2];
    #pragma unroll
    for (int mi = 0; mi < 2; ++mi)
      #pragma unroll
      for (int kk = 0; kk < 2; ++kk)
        xb[mi][kk] = *(const bf16x8*)&xw16[mi * 16 + lrow][kk * 32 + q * 8];

    f32x4 acc[16][2] = {};
    #pragma unroll
    for (int t16 = 0; t16 < 16; ++t16)
      #pragma unroll
      for (int kk = 0; kk < 2; ++kk) {
        bf16x8 a = *(const bf16x8*)&hkb[(size_t)(tw + t16 * 16 + lrow) * 64 + kk * 32 + q * 8];
        #pragma unroll
        for (int mi = 0; mi < 2; ++mi)
          acc[t16][mi] = __builtin_amdgcn_mfma_f32_16x16x32_bf16(a, xb[mi][kk], acc[t16][mi], 0, 0, 0);
      }

    float ss[2] = {0.f, 0.f};
    #pragma unroll
    for (int t16 = 0; t16 < 16; ++t16)
      #pragma unroll
      for (int mi = 0; mi < 2; ++mi)
        #pragma unroll
        for (int r = 0; r < 4; ++r)
          ss[mi] += acc[t16][mi][r] * acc[t16][mi][r];
    #pragma unroll
    for (int mi = 0; mi < 2; ++mi) {
      ss[mi] += __shfl_xor(ss[mi], 16, 64);
      ss[mi] += __shfl_xor(ss[mi], 32, 64);
    }
    if (q == 0) { redn[wave][0][lrow] = ss[0]; redn[wave][1][lrow] = ss[1]; }
    __syncthreads();
    float scale[2];
    #pragma unroll
    for (int mi = 0; mi < 2; ++mi) {
      float t = redn[0][mi][lrow] + redn[1][mi][lrow] + redn[2][mi][lrow] + redn[3][mi][lrow];
      scale[mi] = 32.0f * rsqrtf(fmaxf(t, 1e-20f));
    }

    f32x4 wva[2][4] = {};
    #pragma unroll
    for (int c = 0; c < 2; ++c) {
      #pragma unroll
      for (int t8 = 0; t8 < 8; ++t8) {
        const int t16 = c * 8 + t8;
        #pragma unroll
        for (int mi = 0; mi < 2; ++mi) {
          float g0 = gelu_fast(acc[t16][mi][0] * scale[mi]);
          float g1 = gelu_fast(acc[t16][mi][1] * scale[mi]);
          float g2 = gelu_fast(acc[t16][mi][2] * scale[mi]);
          float g3 = gelu_fast(acc[t16][mi][3] * scale[mi]);
          u32x2 pw;
          pw[0] = (unsigned)f2b(g0) | ((unsigned)f2b(g1) << 16);
          pw[1] = (unsigned)f2b(g2) | ((unsigned)f2b(g3) << 16);
          *(u32x2*)&Pl[wave][mi * 16 + lrow][t8 * 16 + q * 4] = pw;
        }
      }
      #pragma unroll
      for (int kc = 0; kc < 4; ++kc) {
        bf16x8 pa0 = *(const bf16x8*)&Pl[wave][lrow][kc * 32 + q * 8];
        bf16x8 pa1 = *(const bf16x8*)&Pl[wave][16 + lrow][kc * 32 + q * 8];
        #pragma unroll
        for (int nt = 0; nt < 4; ++nt) {
          bf16x8 b = *(const bf16x8*)&hvTb[(size_t)(nt * 16 + lrow) * 1024 +
                                           tw + c * 128 + kc * 32 + q * 8];
          wva[0][nt] = __builtin_amdgcn_mfma_f32_16x16x32_bf16(pa0, b, wva[0][nt], 0, 0, 0);
          wva[1][nt] = __builtin_amdgcn_mfma_f32_16x16x32_bf16(pa1, b, wva[1][nt], 0, 0, 0);
        }
      }
    }

    #pragma unroll
    for (int mi = 0; mi < 2; ++mi)
      #pragma unroll
      for (int nt = 0; nt < 4; ++nt)
        *(f32x4*)&redw[wave][mi][nt][lane][0] = wva[mi][nt];
    __syncthreads();
    #pragma unroll
    for (int mi = 0; mi < 2; ++mi) {
      f32x4 s = *(const f32x4*)&redw[0][mi][wave][lane][0];
      s += *(const f32x4*)&redw[1][mi][wave][lane][0];
      s += *(const f32x4*)&redw[2][mi][wave][lane][0];
      s += *(const f32x4*)&redw[3][mi][wave][lane][0];
      #pragma unroll
      for (int r = 0; r < 4; ++r) {
        int m = mi * 16 + q * 4 + r, j = wave * 16 + lrow;
        wvs[m * 64 + (((j >> 3) ^ (m & 7)) << 3) + (j & 7)] = f2b(s[r]);
      }
    }
    __syncthreads();
  }

  // ================= phase 3: out32x2048 = wv32 @ Wv2T^T (nt stores) =================
  {
    u16x8 wR[4];

#define P3_LOAD(fcx)                                                                      \
    do { _Pragma("unroll") for (int i = 0; i < 4; ++i) {                                  \
      int lin = (wave * 4 + i) * 64 + lane; int frow = lin >> 3, u = lin & 7;             \
      wR[i] = *(const u16x8*)&Wv2Tb[(size_t)((fcx) * 128 + frow) * 64 + u * 8];           \
    } } while (0)
#define P3_WRITE(buf)                                                                     \
    do { _Pragma("unroll") for (int i = 0; i < 4; ++i) {                                  \
      int lin = (wave * 4 + i) * 64 + lane; int frow = lin >> 3, u = lin & 7;             \
      *(u16x8*)&Ws[(buf) * 8192 + frow * 64 + ((u ^ (frow & 7)) << 3)] = wR[i];           \
    } } while (0)

    P3_LOAD(0);
    P3_WRITE(0);
    P3_LOAD(1);

    bf16x8 bw[2][2];
    #pragma unroll
    for (int mt = 0; mt < 2; ++mt)
      #pragma unroll
      for (int kk = 0; kk < 2; ++kk) {
        int row = mt * 16 + lrow;
        bw[mt][kk] = *(const bf16x8*)&wvs[row * 64 + (((kk * 4 + q) ^ (row & 7)) << 3)];
      }
    __syncthreads();

    #pragma unroll 1
    for (int fc = 0; fc < 16; ++fc) {
      const int cb = fc & 1, nb = cb ^ 1, ob = fc & 1;
      if (fc + 1 < 16) P3_WRITE(nb);         // regs for fc+1 (loaded at fc-1)
      if (fc + 2 < 16) P3_LOAD(fc + 2);
      #pragma unroll
      for (int ftl = 0; ftl < 2; ++ftl) {
        const int ft = wave * 2 + ftl;
        f32x4 a2[2] = {};
        #pragma unroll
        for (int kk = 0; kk < 2; ++kk) {
          const int frow = ft * 16 + lrow;
          bf16x8 af = *(const bf16x8*)&Ws[cb * 8192 + frow * 64 + (((kk * 4 + q) ^ (frow & 7)) << 3)];
          #pragma unroll
          for (int mt = 0; mt < 2; ++mt)
            a2[mt] = __builtin_amdgcn_mfma_f32_16x16x32_bf16(af, bw[mt][kk], a2[mt], 0, 0, 0);
        }
        #pragma unroll
        for (int mt = 0; mt < 2; ++mt)
          *(f32x4*)&oS[ob][mt * 16 + lrow][ft * 16 + q * 4] = a2[mt];
      }
      __syncthreads();
      // coalesced non-temporal stores: 2 rows x 512B per instr; no L3 allocate
      #pragma unroll
      for (int i = 0; i < 4; ++i) {
        int row = (wave * 4 + i) * 2 + (lane >> 5);
        int c = (lane & 31) * 4;
        f32x4 v = *(const f32x4*)&oS[ob][row][c];
        __builtin_nontemporal_store(v, (f32x4*)&out[(size_t)(r0 + row) * 2048 + fc * 128 + c]);
      }
    }
#undef P3_LOAD
#undef P3_WRITE
  }
}

extern "C" void kernel_launch(void* const* d_in, const int* in_sizes, int n_in,
                              void* d_out, int out_size, void* d_ws, size_t ws_size,
                              hipStream_t stream) {
  (void)in_sizes; (void)n_in; (void)out_size; (void)ws_size;
  const float* x      = (const float*)d_in[0];
  const float* tokens = (const float*)d_in[1];
  const float* Wk1    = (const float*)d_in[2];
  const float* Wk2    = (const float*)d_in[3];
  const float* Wv1    = (const float*)d_in[4];
  const float* Wv2    = (const float*)d_in[5];

  char* ws = (char*)d_ws;
  unsigned short* hkb   = (unsigned short*)(ws);                    // 128 KB
  unsigned short* hvTb  = (unsigned short*)(ws + 131072);           // 128 KB
  unsigned short* Wk2b  = (unsigned short*)(ws + 262144);           // 256 KB
  unsigned short* Wv2Tb = (unsigned short*)(ws + 524288);           // 256 KB

  hipLaunchKernelGGL(prep, dim3(304), dim3(256), 0, stream,
                     tokens, Wk1, Wv1, Wk2, Wv2, hkb, hvTb, Wk2b, Wv2Tb);
  hipLaunchKernelGGL(mainK, dim3(512), dim3(256), 0, stream,
                     x, Wk2b, hkb, hvTb, Wv2Tb, (float*)d_out);
}